// Round 15
// baseline (354.556 us; speedup 1.0000x reference)
//
#include <hip/hip_runtime.h>
#include <math.h>
#include <float.h>

#define NB 8
#define NP 4096
#define BN_ (NB*NP)
#define KNN 5
#define JCH 512
#define NJC (NP/JCH)
#define TW 2432            // real tile width (ranks)
#define TE (TW + 128)      // + 64 sentinel pads each side = 2560 entries = 40960 B

typedef unsigned short u16;
typedef __attribute__((ext_vector_type(8))) __bf16 bf16x8;
typedef __attribute__((ext_vector_type(4))) float f32x4;

__device__ __forceinline__ u16 f2bf(float x){
  unsigned u = __float_as_uint(x);
  u += 0x7fff + ((u>>16)&1);          // RNE
  return (u16)(u>>16);
}
__device__ __forceinline__ float bf2f(u16 h){ return __uint_as_float(((unsigned)h)<<16); }

// ---------------- preprocessing (exact fp32) ----------------

__global__ void k_centroid(const float* __restrict__ pc, float* __restrict__ dcent,
                           int* __restrict__ rankb) {
  int b = blockIdx.x, tid = threadIdx.x;
  const float* px = pc + (size_t)b*3*NP;
  const float* py = px + NP;
  const float* pz = py + NP;
  double sx=0, sy=0, sz=0;
  for (int n = tid; n < NP; n += 256) { sx += px[n]; sy += py[n]; sz += pz[n]; }
  __shared__ double rx[256], ry[256], rz[256];
  rx[tid]=sx; ry[tid]=sy; rz[tid]=sz;
  __syncthreads();
  for (int s = 128; s > 0; s >>= 1) {
    if (tid < s) { rx[tid]+=rx[tid+s]; ry[tid]+=ry[tid+s]; rz[tid]+=rz[tid+s]; }
    __syncthreads();
  }
  __shared__ float cxs, cys, czs;
  if (tid == 0) {
    cxs = (float)(rx[0]/NP); cys = (float)(ry[0]/NP); czs = (float)(rz[0]/NP);
  }
  __syncthreads();
  float cx = cxs, cy = cys, cz = czs;
  for (int n = tid; n < NP; n += 256) {
    float dx = __fsub_rn(px[n], cx);
    float dy = __fsub_rn(py[n], cy);
    float dz = __fsub_rn(pz[n], cz);
    float d = __fadd_rn(__fadd_rn(__fmul_rn(dx,dx), __fmul_rn(dy,dy)), __fmul_rn(dz,dz));
    dcent[b*NP + n] = d;
    rankb[b*NP + n] = 0;
  }
}

__global__ void __launch_bounds__(256) k_rank_part(const float* __restrict__ dcent,
                                                   int* __restrict__ rank) {
  int jc = blockIdx.x, ic = blockIdx.y, b = blockIdx.z;
  __shared__ __attribute__((aligned(16))) float d[JCH];
  int j0 = jc*JCH;
  for (int n = threadIdx.x; n < JCH; n += 256) d[n] = dcent[b*NP + j0 + n];
  __syncthreads();
  int i = ic*256 + threadIdx.x;
  float di = dcent[b*NP + i];
  int cnt = 0;
  #pragma unroll 4
  for (int n = 0; n < JCH; n += 4) {
    float4 dv = *(const float4*)&d[n];     // ds_read_b128: 4 candidates per LDS op
    cnt += (dv.x < di) || (dv.x == di && (j0 + n + 0) < i);
    cnt += (dv.y < di) || (dv.y == di && (j0 + n + 1) < i);
    cnt += (dv.z < di) || (dv.z == di && (j0 + n + 2) < i);
    cnt += (dv.w < di) || (dv.w == di && (j0 + n + 3) < i);
  }
  atomicAdd(&rank[b*NP + i], cnt);
}

// scatter + build rank-sorted tables + zero deg (merged)
__global__ void k_scatprep(const float* __restrict__ pc, const int* __restrict__ rank,
                           const float* __restrict__ dcent,
                           int* __restrict__ ord, float4* __restrict__ srt,
                           float* __restrict__ rcv, int* __restrict__ deg) {
  int idx = blockIdx.x*256 + threadIdx.x;
  int b = idx >> 12, i = idx & (NP-1);
  int r = rank[idx];
  ord[b*NP + r] = i;
  const float* base = pc + (size_t)b*3*NP;
  float x = base[i], y = base[NP+i], z = base[2*NP+i];
  float sq = __fadd_rn(__fadd_rn(__fmul_rn(x,x), __fmul_rn(y,y)), __fmul_rn(z,z));
  float4 v; v.x=x; v.y=y; v.z=z; v.w=sq;
  srt[b*NP + r] = v;
  rcv[b*NP + r] = sqrtf(dcent[idx]);
  deg[idx] = 0;
}

// ---- annulus KNN v4.2: windowed tile (40 KB -> 4 blocks/CU), 16 lanes/node ----
#define INS(dist, q) \
  if (dist < b4) { \
    if (dist < b3) { b4=b3; r4=r3; \
      if (dist < b2) { b3=b2; r3=r2; \
        if (dist < b1) { b2=b1; r2=r1; \
          if (dist < b0) { b1=b0; r1=r0; b0=dist; r0=(q); } \
          else { b1=dist; r1=(q); } \
        } else { b2=dist; r2=(q); } \
      } else { b3=dist; r3=(q); } \
    } else { b4=dist; r4=(q); } \
  }

__global__ void __launch_bounds__(512) k_knn_ann4(const float4* __restrict__ srt,
                                                  const float* __restrict__ rc,
                                                  const int* __restrict__ ord,
                                                  int* __restrict__ nbr,
                                                  int* __restrict__ deg) {
  __shared__ float4 tile[TE];        // 40960 B
  const int b = blockIdx.x >> 7;     // 128 blocks per batch, 32 nodes each
  const int blk = blockIdx.x & 127;
  const int gbase = b*NP;
  const int base = blk*32;
  const int tlo = base - 1200;       // real zone covers ranks [tlo, tlo+TW)
  const int thi = tlo + TW;          // = base + 1232
  for (int t = threadIdx.x; t < TE; t += 512) {
    int q = tlo + t - 64;
    bool real = ((unsigned)(t - 64) < (unsigned)TW) && ((unsigned)q < NP);
    if (real) tile[t] = srt[gbase + q];
    else { float4 s4; s4.x=0.f; s4.y=0.f; s4.z=0.f; s4.w=1e30f; tile[t] = s4; }
  }
  __syncthreads();

  const int lane = threadIdx.x & 63;
  const int wv   = threadIdx.x >> 6;   // 8 waves
  const int grp  = lane >> 4;          // 4 nodes per wave
  const int sub  = lane & 15;          // 16 lanes per node
  const int s_i  = base + wv*4 + grp;

  float4 p = tile[s_i - tlo + 64];
  float xi=p.x, yi=p.y, zi=p.z, sqi=p.w;
  float ri = rc[gbase + s_i];

  const bool is_hi = (sub < 8);
  const int step = is_hi ? 8 : -8;
  const int jdead = is_hi ? (thi + 7) : (tlo - 8);   // parked in sentinel pads
  int j = is_hi ? (s_i + sub) : (s_i - 1 - (sub - 8));
  bool alive = ((unsigned)j < NP);
  if (!alive) j = jdead;

  float b0=FLT_MAX, b1=FLT_MAX, b2=FLT_MAX, b3=FLT_MAX, b4=FLT_MAX;
  int r0=0, r1=0, r2=0, r3=0, r4=0;

  while (__ballot(alive)) {
    bool fast = (!alive) || (is_hi ? (j + 56 < thi) : (j - 56 >= tlo));
    if (__ballot(!fast) == 0ULL) {
      // whole batch inside the tile (dead lanes read sentinel pads = 1e30)
      float4 jp[8];
      #pragma unroll
      for (int t = 0; t < 8; ++t) jp[t] = tile[j - tlo + 64 + step*t];
      #pragma unroll
      for (int t = 0; t < 8; ++t) {
        float dot = __fadd_rn(__fadd_rn(__fmul_rn(xi,jp[t].x), __fmul_rn(yi,jp[t].y)), __fmul_rn(zi,jp[t].z));
        float dist = __fsub_rn(__fadd_rn(sqi, jp[t].w), __fmul_rn(2.0f, dot));
        if (__ballot(dist < b4)) { INS(dist, j + step*t) }
      }
    } else {
      // rare: batch crosses tile edge -> per-candidate tile/global select
      #pragma unroll
      for (int t = 0; t < 8; ++t) {
        int jt = j + step*t;
        float4 q4;
        if ((unsigned)(jt - tlo) < (unsigned)TW) {
          q4 = tile[jt - tlo + 64];
        } else {
          int qc = jt < 0 ? 0 : (jt > NP-1 ? NP-1 : jt);
          q4 = srt[gbase + qc];
          if (!(alive && (unsigned)jt < NP)) q4.w = 1e30f;  // sentinel semantics
        }
        float dot = __fadd_rn(__fadd_rn(__fmul_rn(xi,q4.x), __fmul_rn(yi,q4.y)), __fmul_rn(zi,q4.z));
        float dist = __fsub_rn(__fadd_rn(sqi, q4.w), __fmul_rn(2.0f, dot));
        if (__ballot(dist < b4)) { INS(dist, jt) }
      }
    }
    // group-shared prune bound (min of per-lane b4 over the 16-lane group)
    float bm = b4;
    bm = fminf(bm, __shfl_xor(bm, 1));
    bm = fminf(bm, __shfl_xor(bm, 2));
    bm = fminf(bm, __shfl_xor(bm, 4));
    bm = fminf(bm, __shfl_xor(bm, 8));
    float T = bm*1.0002f + 1e-9f;
    int qe = j + step*7;
    qe = qe < 0 ? 0 : (qe > NP-1 ? NP-1 : qe);
    float dr = fabsf(ri - rc[gbase + qe]);
    bool nextin = ((unsigned)(j + step*8) < NP);
    alive = alive && nextin && (__fmul_rn(dr,dr) < T);
    j = alive ? (j + step*8) : jdead;
  }

  // merge the 16 sorted-5 lists within the group (xor butterfly)
  #pragma unroll
  for (int m = 1; m <= 8; m <<= 1) {
    float c0=__shfl_xor(b0,m), c1=__shfl_xor(b1,m), c2=__shfl_xor(b2,m),
          c3=__shfl_xor(b3,m), c4=__shfl_xor(b4,m);
    int   s0=__shfl_xor(r0,m), s1=__shfl_xor(r1,m), s2=__shfl_xor(r2,m),
          s3=__shfl_xor(r3,m), s4=__shfl_xor(r4,m);
    if (c0 < b4) { INS(c0, s0)
      if (c1 < b4) { INS(c1, s1)
        if (c2 < b4) { INS(c2, s2)
          if (c3 < b4) { INS(c3, s3)
            if (c4 < b4) { INS(c4, s4) }
          }
        }
      }
    }
  }

  if (sub == 0) {
    int oi = ord[gbase + s_i];
    int node = gbase + oi;
    int nb = node*KNN;
    int o0 = gbase + ord[gbase+r0], o1 = gbase + ord[gbase+r1], o2 = gbase + ord[gbase+r2];
    int o3 = gbase + ord[gbase+r3], o4 = gbase + ord[gbase+r4];
    nbr[nb+0]=o0; nbr[nb+1]=o1; nbr[nb+2]=o2; nbr[nb+3]=o3; nbr[nb+4]=o4;
    atomicAdd(&deg[o0],1); atomicAdd(&deg[o1],1); atomicAdd(&deg[o2],1);
    atomicAdd(&deg[o3],1); atomicAdd(&deg[o4],1);
  }
}

// ---------------- all weights fp32->bf16 in one launch ----------------
__global__ void k_cvt_all(const float* __restrict__ w2, const float* __restrict__ w3,
                          const float* __restrict__ w4, const float* __restrict__ gc1,
                          const float* __restrict__ gc2, const float* __restrict__ gc3,
                          const float* __restrict__ fc1, const float* __restrict__ fc2,
                          u16* o2, u16* o3, u16* o4, u16* og1, u16* og2, u16* og3,
                          u16* of1, u16* of2) {
  int i = blockIdx.x*256 + threadIdx.x;
  if (i < 4096) { o2[i] = f2bf(w2[i]); return; } i -= 4096;
  if (i < 4096) { o3[i] = f2bf(w3[i]); return; } i -= 4096;
  if (i < 8192) { o4[i] = f2bf(w4[i]); return; } i -= 8192;
  if (i < 16384) { int n=i>>7, k=i&127; og1[i] = f2bf(gc1[k*128+n]); return; } i -= 16384;
  if (i < 16384) { int n=i>>7, k=i&127; og2[i] = f2bf(gc2[k*128+n]); return; } i -= 16384;
  if (i < 32768) { int n=i>>7, k=i&127; og3[i] = f2bf(gc3[k*256+n]); return; } i -= 32768;
  if (i < 131072) { of1[i] = f2bf(fc1[i]); return; } i -= 131072;
  if (i < 131072) { of2[i] = f2bf(fc2[i]); }
}

// ---------------- fused conv stack: conv1 (3->64) + conv2/3 (64->64) + conv4 (64->128) ----
__global__ void __launch_bounds__(256) k_convstack(
    const float* __restrict__ pc, const int* __restrict__ ord,
    const float* __restrict__ w1, const float* __restrict__ g1, const float* __restrict__ b1,
    const u16* __restrict__ wb2, const float* __restrict__ g2, const float* __restrict__ b2,
    const u16* __restrict__ wb3, const float* __restrict__ g3, const float* __restrict__ b3,
    const u16* __restrict__ wb4, const float* __restrict__ g4, const float* __restrict__ b4,
    u16* __restrict__ feat, float* __restrict__ pooled) {
  __shared__ float xs[128], ys[128], zs[128];
  __shared__ u16 hA[128*64];
  __shared__ u16 hB[128*64];
  __shared__ u16 wbuf[128*64];
  const int tid = threadIdx.x;
  const int m0 = blockIdx.x * 128;
  const int b = m0 >> 12;
  if (blockIdx.x == 0) pooled[tid] = 0.0f;
  if (tid < 128) {
    int j = ord[m0 + tid];
    const float* base = pc + (size_t)b*3*NP;
    xs[tid] = base[j]; ys[tid] = base[NP + j]; zs[tid] = base[2*NP + j];
  }
  #pragma unroll
  for (int it = 0; it < 2; ++it) {
    int t = tid + it*256;
    int row = t >> 3, lc = t & 7;
    uint4 v = *(const uint4*)(wb2 + ((size_t)row*64 + lc*8));
    *(uint4*)&wbuf[row*64 + ((lc ^ (row&7))*8)] = v;
  }
  __syncthreads();

  for (int idx = tid; idx < 128*64; idx += 256) {
    int n = idx >> 6, o = idx & 63;
    float x = xs[n], y = ys[n], z = zs[n];
    float acc = x*w1[o*3+0] + y*w1[o*3+1] + z*w1[o*3+2];
    float v = fmaxf(acc*g1[o] + b1[o], 0.0f);
    hA[n*64 + (((o>>3) ^ (n&7))*8) + (o&7)] = f2bf(v);
  }
  __syncthreads();

  const int w = tid >> 6, l = tid & 63;
  const int wm = w & 1, wn = w >> 1;
  const int fm = l & 15, fk = l >> 4;

  // ---- conv2 ----
  {
    f32x4 acc[4][2];
    #pragma unroll
    for (int i=0;i<4;++i) { acc[i][0]=(f32x4){0,0,0,0}; acc[i][1]=(f32x4){0,0,0,0}; }
    #pragma unroll
    for (int ks=0; ks<2; ++ks){
      bf16x8 af[4], bfr[2];
      #pragma unroll
      for (int mf=0; mf<4; ++mf){
        int row = wm*64 + mf*16 + fm; int ck = ks*4 + fk;
        af[mf] = *(const bf16x8*)&hA[row*64 + ((ck ^ (row&7))*8)];
      }
      #pragma unroll
      for (int nf=0; nf<2; ++nf){
        int row = wn*32 + nf*16 + fm; int ck = ks*4 + fk;
        bfr[nf] = *(const bf16x8*)&wbuf[row*64 + ((ck ^ (row&7))*8)];
      }
      #pragma unroll
      for (int mf=0; mf<4; ++mf)
        #pragma unroll
        for (int nf=0; nf<2; ++nf)
          acc[mf][nf] = __builtin_amdgcn_mfma_f32_16x16x32_bf16(af[mf], bfr[nf], acc[mf][nf], 0, 0, 0);
    }
    #pragma unroll
    for (int mf=0; mf<4; ++mf)
      #pragma unroll
      for (int r=0;r<4;++r){
        int row = wm*64 + mf*16 + fk*4 + r;
        #pragma unroll
        for (int nf=0;nf<2;++nf){
          int col = wn*32 + nf*16 + fm;
          float v = fmaxf(acc[mf][nf][r]*g2[col] + b2[col], 0.f);
          hB[row*64 + (((col>>3) ^ (row&7))*8) + (col&7)] = f2bf(v);
        }
      }
  }
  __syncthreads();
  #pragma unroll
  for (int it = 0; it < 2; ++it) {
    int t = tid + it*256;
    int row = t >> 3, lc = t & 7;
    uint4 v = *(const uint4*)(wb3 + ((size_t)row*64 + lc*8));
    *(uint4*)&wbuf[row*64 + ((lc ^ (row&7))*8)] = v;
  }
  __syncthreads();

  // ---- conv3 ----
  {
    f32x4 acc[4][2];
    #pragma unroll
    for (int i=0;i<4;++i) { acc[i][0]=(f32x4){0,0,0,0}; acc[i][1]=(f32x4){0,0,0,0}; }
    #pragma unroll
    for (int ks=0; ks<2; ++ks){
      bf16x8 af[4], bfr[2];
      #pragma unroll
      for (int mf=0; mf<4; ++mf){
        int row = wm*64 + mf*16 + fm; int ck = ks*4 + fk;
        af[mf] = *(const bf16x8*)&hB[row*64 + ((ck ^ (row&7))*8)];
      }
      #pragma unroll
      for (int nf=0; nf<2; ++nf){
        int row = wn*32 + nf*16 + fm; int ck = ks*4 + fk;
        bfr[nf] = *(const bf16x8*)&wbuf[row*64 + ((ck ^ (row&7))*8)];
      }
      #pragma unroll
      for (int mf=0; mf<4; ++mf)
        #pragma unroll
        for (int nf=0; nf<2; ++nf)
          acc[mf][nf] = __builtin_amdgcn_mfma_f32_16x16x32_bf16(af[mf], bfr[nf], acc[mf][nf], 0, 0, 0);
    }
    #pragma unroll
    for (int mf=0; mf<4; ++mf)
      #pragma unroll
      for (int r=0;r<4;++r){
        int row = wm*64 + mf*16 + fk*4 + r;
        #pragma unroll
        for (int nf=0;nf<2;++nf){
          int col = wn*32 + nf*16 + fm;
          float v = fmaxf(acc[mf][nf][r]*g3[col] + b3[col], 0.f);
          hA[row*64 + (((col>>3) ^ (row&7))*8) + (col&7)] = f2bf(v);
        }
      }
  }
  __syncthreads();
  #pragma unroll
  for (int it = 0; it < 4; ++it) {
    int t = tid + it*256;
    int row = t >> 3, lc = t & 7;
    uint4 v = *(const uint4*)(wb4 + ((size_t)row*64 + lc*8));
    *(uint4*)&wbuf[row*64 + ((lc ^ (row&7))*8)] = v;
  }
  __syncthreads();

  // ---- conv4 ----
  {
    f32x4 acc[4][4];
    #pragma unroll
    for (int i=0;i<4;++i)
      #pragma unroll
      for (int jn=0;jn<4;++jn) acc[i][jn]=(f32x4){0,0,0,0};
    #pragma unroll
    for (int ks=0; ks<2; ++ks){
      bf16x8 af[4], bfr[4];
      #pragma unroll
      for (int mf=0; mf<4; ++mf){
        int row = wm*64 + mf*16 + fm; int ck = ks*4 + fk;
        af[mf] = *(const bf16x8*)&hA[row*64 + ((ck ^ (row&7))*8)];
      }
      #pragma unroll
      for (int nf=0; nf<4; ++nf){
        int row = wn*64 + nf*16 + fm; int ck = ks*4 + fk;
        bfr[nf] = *(const bf16x8*)&wbuf[row*64 + ((ck ^ (row&7))*8)];
      }
      #pragma unroll
      for (int mf=0; mf<4; ++mf)
        #pragma unroll
        for (int nf=0; nf<4; ++nf)
          acc[mf][nf] = __builtin_amdgcn_mfma_f32_16x16x32_bf16(af[mf], bfr[nf], acc[mf][nf], 0, 0, 0);
    }
    #pragma unroll
    for (int mf=0; mf<4; ++mf)
      #pragma unroll
      for (int r=0;r<4;++r){
        int row = m0 + wm*64 + mf*16 + fk*4 + r;
        #pragma unroll
        for (int nf=0;nf<4;++nf){
          int col = wn*64 + nf*16 + fm;
          float v = fmaxf(acc[mf][nf][r]*g4[col] + b4[col], 0.f);
          feat[(size_t)row*128 + col] = f2bf(v);
        }
      }
  }
}

// ---------------- bf16 MFMA GEMM: C = act(A[M,K] * W[N,K]^T) ----------------
// mode 0: bf16 out = relu(acc*gamma[col]+beta[col])
// mode 1: bf16 out = acc * (1/sqrt(max(deg[row],1)))
// mode 3: no C write; atomicMax global max-pool of relu(acc*gamma[col]+beta[col]) into Cout
template<int BNT>
__global__ __launch_bounds__(256) void gemm_bf16(
    const u16* __restrict__ A, const u16* __restrict__ W,
    const float* __restrict__ gamma, const float* __restrict__ beta,
    const int* __restrict__ degp, void* __restrict__ Cout,
    int K, int Nc, int mode) {
  constexpr int NF = BNT/32;
  __shared__ u16 As[128*64];
  __shared__ u16 Bs[BNT*64];
  const int tid = threadIdx.x;
  const int w = tid >> 6, l = tid & 63;
  const int m0 = blockIdx.x*128, n0 = blockIdx.y*BNT;
  const int wm = w & 1, wn = w >> 1;
  const int lr = l >> 3;
  const int lc = l & 7;
  const int fm = l & 15, fk = l >> 4;

  f32x4 acc[4][NF];
  #pragma unroll
  for (int i=0;i<4;++i)
    #pragma unroll
    for (int j=0;j<NF;++j) acc[i][j] = (f32x4){0.f,0.f,0.f,0.f};

  for (int k0 = 0; k0 < K; k0 += 64) {
    #pragma unroll
    for (int t=0;t<4;++t){
      int row = (w*4 + t)*8 + lr;
      uint4 v = *(const uint4*)(A + ((size_t)(m0+row)*K + k0 + lc*8));
      *(uint4*)&As[row*64 + ((lc ^ (row&7))*8)] = v;
    }
    #pragma unroll
    for (int t=0;t<NF;++t){
      int row = (w*NF + t)*8 + lr;
      uint4 v = *(const uint4*)(W + ((size_t)(n0+row)*K + k0 + lc*8));
      *(uint4*)&Bs[row*64 + ((lc ^ (row&7))*8)] = v;
    }
    __syncthreads();
    #pragma unroll
    for (int ks=0; ks<2; ++ks){
      bf16x8 af[4], bfr[NF];
      #pragma unroll
      for (int mf=0; mf<4; ++mf){
        int row = wm*64 + mf*16 + fm;
        int ck = ks*4 + fk;
        af[mf] = *(const bf16x8*)&As[row*64 + ((ck ^ (row&7))*8)];
      }
      #pragma unroll
      for (int nf=0; nf<NF; ++nf){
        int row = wn*(BNT/2) + nf*16 + fm;
        int ck = ks*4 + fk;
        bfr[nf] = *(const bf16x8*)&Bs[row*64 + ((ck ^ (row&7))*8)];
      }
      #pragma unroll
      for (int mf=0; mf<4; ++mf)
        #pragma unroll
        for (int nf=0; nf<NF; ++nf)
          acc[mf][nf] = __builtin_amdgcn_mfma_f32_16x16x32_bf16(af[mf], bfr[nf], acc[mf][nf], 0, 0, 0);
    }
    __syncthreads();
  }

  const int col_base = n0 + wn*(BNT/2);
  if (mode == 1) {
    u16* C = (u16*)Cout;
    #pragma unroll
    for (int mf=0; mf<4; ++mf){
      #pragma unroll
      for (int r=0;r<4;++r){
        int row = m0 + wm*64 + mf*16 + fk*4 + r;
        int d = degp[row]; if (d < 1) d = 1;
        float rs = 1.0f / sqrtf((float)d);
        #pragma unroll
        for (int nf=0;nf<NF;++nf){
          int col = col_base + nf*16 + fm;
          C[(size_t)row*Nc + col] = f2bf(acc[mf][nf][r]*rs);
        }
      }
    }
  } else if (mode == 3) {
    unsigned int* pool = (unsigned int*)Cout;
    float gv[NF], bv[NF], cm[NF];
    #pragma unroll
    for (int nf=0;nf<NF;++nf){
      int col = col_base + nf*16 + fm;
      gv[nf] = gamma[col]; bv[nf] = beta[col];
      cm[nf] = 0.0f;
    }
    #pragma unroll
    for (int mf=0; mf<4; ++mf)
      #pragma unroll
      for (int r=0;r<4;++r)
        #pragma unroll
        for (int nf=0;nf<NF;++nf){
          float v = fmaxf(acc[mf][nf][r]*gv[nf] + bv[nf], 0.f);
          cm[nf] = fmaxf(cm[nf], v);
        }
    #pragma unroll
    for (int nf=0;nf<NF;++nf){
      float m = cm[nf];
      m = fmaxf(m, __shfl_xor(m, 16));
      m = fmaxf(m, __shfl_xor(m, 32));
      if (fk == 0)
        atomicMax(&pool[col_base + nf*16 + fm], __float_as_uint(m));
    }
  } else {
    float gv[NF], bv[NF];
    #pragma unroll
    for (int nf=0;nf<NF;++nf){
      int col = col_base + nf*16 + fm;
      gv[nf] = gamma[col]; bv[nf] = beta[col];
    }
    #pragma unroll
    for (int mf=0; mf<4; ++mf){
      #pragma unroll
      for (int r=0;r<4;++r){
        int row = m0 + wm*64 + mf*16 + fk*4 + r;
        #pragma unroll
        for (int nf=0;nf<NF;++nf){
          int col = col_base + nf*16 + fm;
          float v = fmaxf(acc[mf][nf][r]*gv[nf] + bv[nf], 0.f);
          ((u16*)Cout)[(size_t)row*Nc + col] = f2bf(v);
        }
      }
    }
  }
}

// ---------------- GCN aggregate (bf16 in/out, fp32 math) ----------------
__global__ void k_agg_bf(const u16* __restrict__ hw, const int* __restrict__ nbr,
                         const float* __restrict__ bias, u16* __restrict__ outp,
                         int F, int do_relu) {
  int per = F >> 3;
  int gid = blockIdx.x*256 + threadIdx.x;
  int i = gid / per;
  int f = (gid - i*per) * 8;
  const int* nb = nbr + i*KNN;
  float s[8] = {0,0,0,0,0,0,0,0};
  #pragma unroll
  for (int k = 0; k < KNN; ++k) {
    uint4 v = *(const uint4*)(hw + (size_t)nb[k]*F + f);
    const u16* h = (const u16*)&v;
    #pragma unroll
    for (int j=0;j<8;++j) s[j] += bf2f(h[j]);
  }
  const float ninv = 0.44721359549995793f;  // rsqrt(5): deg_in == 5 always
  u16 o[8];
  #pragma unroll
  for (int j=0;j<8;++j){
    float v = s[j]*ninv + bias[f+j];
    if (do_relu) v = fmaxf(v, 0.f);
    o[j] = f2bf(v);
  }
  *(uint4*)&outp[(size_t)i*F + f] = *(const uint4*)o;
}

// ---------------- final 256 -> 128 GEMV (fp32) ----------------
__global__ void k_fc3(const float* __restrict__ pooled, const float* __restrict__ w,
                      const float* __restrict__ bias, float* __restrict__ outp) {
  __shared__ float p[256];
  int tid = threadIdx.x;
  p[tid] = pooled[tid];
  p[tid + 128] = pooled[tid + 128];
  __syncthreads();
  float s = 0.0f;
  for (int i = 0; i < 256; ++i) s = fmaf(w[tid*256 + i], p[i], s);
  outp[tid] = s + bias[tid];
}

extern "C" void kernel_launch(void* const* d_in, const int* in_sizes, int n_in,
                              void* d_out, int out_size, void* d_ws, size_t ws_size,
                              hipStream_t stream) {
  const float* pc   = (const float*)d_in[0];
  const float* w1   = (const float*)d_in[1];
  const float* g1   = (const float*)d_in[2];
  const float* b1   = (const float*)d_in[3];
  const float* w2   = (const float*)d_in[4];
  const float* g2   = (const float*)d_in[5];
  const float* b2   = (const float*)d_in[6];
  const float* w3   = (const float*)d_in[7];
  const float* g3   = (const float*)d_in[8];
  const float* b3   = (const float*)d_in[9];
  const float* w4   = (const float*)d_in[10];
  const float* g4   = (const float*)d_in[11];
  const float* b4   = (const float*)d_in[12];
  const float* gc1w = (const float*)d_in[13];
  const float* gc1b = (const float*)d_in[14];
  const float* gc2w = (const float*)d_in[15];
  const float* gc2b = (const float*)d_in[16];
  const float* gc3w = (const float*)d_in[17];
  const float* gc3b = (const float*)d_in[18];
  const float* fc1w = (const float*)d_in[19];
  const float* f1g  = (const float*)d_in[20];
  const float* f1b  = (const float*)d_in[21];
  const float* fc2w = (const float*)d_in[22];
  const float* f2g  = (const float*)d_in[23];
  const float* f2b  = (const float*)d_in[24];
  const float* fc3w = (const float*)d_in[25];
  const float* fc3b = (const float*)d_in[26];
  float* outp = (float*)d_out;

  char* wsb = (char*)d_ws;
  size_t off = 0;
  auto alloc = [&](size_t bytes) -> void* {
    void* p = wsb + off;
    off += (bytes + 255) & ~(size_t)255;
    return p;
  };
  int*   ord    = (int*)  alloc((size_t)BN_*4);
  int*   deg    = (int*)  alloc((size_t)BN_*4);
  int*   rankb  = (int*)  alloc((size_t)BN_*4);
  int*   nbr    = (int*)  alloc((size_t)BN_*KNN*4);
  float* dcent  = (float*)alloc((size_t)BN_*4);
  float* pooled = (float*)alloc(256*4);
  float4* srt   = (float4*)alloc((size_t)BN_*16);
  float* rc     = (float*)alloc((size_t)BN_*4);
  // bf16 weights
  u16* wb2   = (u16*)alloc(64*64*2);
  u16* wb3   = (u16*)alloc(64*64*2);
  u16* wb4   = (u16*)alloc(128*64*2);
  u16* wgc1  = (u16*)alloc(128*128*2);
  u16* wgc2  = (u16*)alloc(128*128*2);
  u16* wgc3  = (u16*)alloc(256*128*2);
  u16* wfc1  = (u16*)alloc(512*256*2);
  u16* wfc2  = (u16*)alloc(256*512*2);
  // bf16 activations
  u16* feat = (u16*)alloc((size_t)BN_*128*2);
  u16* hw   = (u16*)alloc((size_t)BN_*256*2);
  u16* gb1  = (u16*)alloc((size_t)BN_*128*2);
  u16* g3b  = (u16*)alloc((size_t)BN_*256*2);
  u16* z1   = (u16*)alloc((size_t)BN_*512*2);

  k_cvt_all<<<1344, 256, 0, stream>>>(w2, w3, w4, gc1w, gc2w, gc3w, fc1w, fc2w,
                                      wb2, wb3, wb4, wgc1, wgc2, wgc3, wfc1, wfc2);

  // preprocessing (exact fp32)
  k_centroid<<<NB, 256, 0, stream>>>(pc, dcent, rankb);
  k_rank_part<<<dim3(NJC, NP/256, NB), 256, 0, stream>>>(dcent, rankb);
  k_scatprep<<<BN_/256, 256, 0, stream>>>(pc, rankb, dcent, ord, srt, rc, deg);
  k_knn_ann4<<<NB*128, 512, 0, stream>>>(srt, rc, ord, nbr, deg);

  // fused conv stack: conv1 + conv2 + conv3 + conv4 -> feat [BN,128]
  k_convstack<<<BN_/128, 256, 0, stream>>>(pc, ord, w1, g1, b1,
                                           wb2, g2, b2, wb3, g3, b3, wb4, g4, b4,
                                           feat, pooled);

  // GCN 1
  gemm_bf16<128><<<dim3(BN_/128, 1), 256, 0, stream>>>(feat, wgc1, nullptr, nullptr, deg, hw, 128, 128, 1);
  k_agg_bf<<<(BN_*16)/256, 256, 0, stream>>>(hw, nbr, gc1b, gb1, 128, 1);
  // GCN 2
  gemm_bf16<128><<<dim3(BN_/128, 1), 256, 0, stream>>>(gb1, wgc2, nullptr, nullptr, deg, hw, 128, 128, 1);
  k_agg_bf<<<(BN_*16)/256, 256, 0, stream>>>(hw, nbr, gc2b, feat, 128, 1);
  // GCN 3
  gemm_bf16<128><<<dim3(BN_/128, 2), 256, 0, stream>>>(feat, wgc3, nullptr, nullptr, deg, hw, 128, 256, 1);
  k_agg_bf<<<(BN_*32)/256, 256, 0, stream>>>(hw, nbr, gc3b, g3b, 256, 0);

  // head: fc1 -> z1; fc2 fused with global max-pool (mode 3, no C write)
  gemm_bf16<128><<<dim3(BN_/128, 4), 256, 0, stream>>>(g3b, wfc1, f1g, f1b, nullptr, z1, 256, 512, 0);
  gemm_bf16<128><<<dim3(BN_/128, 2), 256, 0, stream>>>(z1, wfc2, f2g, f2b, nullptr, pooled, 512, 256, 3);
  k_fc3<<<1, 128, 0, stream>>>(pooled, fc3w, fc3b, outp);
}

// Round 16
// 331.638 us; speedup vs baseline: 1.0691x; 1.0691x over previous
//
#include <hip/hip_runtime.h>
#include <math.h>
#include <float.h>

#define NB 8
#define NP 4096
#define BN_ (NB*NP)
#define KNN 5
#define JCH 512
#define NJC (NP/JCH)
#define SENT 64

typedef unsigned short u16;
typedef __attribute__((ext_vector_type(8))) __bf16 bf16x8;
typedef __attribute__((ext_vector_type(4))) float f32x4;

__device__ __forceinline__ u16 f2bf(float x){
  unsigned u = __float_as_uint(x);
  u += 0x7fff + ((u>>16)&1);          // RNE
  return (u16)(u>>16);
}
__device__ __forceinline__ float bf2f(u16 h){ return __uint_as_float(((unsigned)h)<<16); }

// ---------------- preprocessing (exact fp32) ----------------

__global__ void k_centroid(const float* __restrict__ pc, float* __restrict__ dcent,
                           int* __restrict__ rankb) {
  int b = blockIdx.x, tid = threadIdx.x;
  const float* px = pc + (size_t)b*3*NP;
  const float* py = px + NP;
  const float* pz = py + NP;
  double sx=0, sy=0, sz=0;
  for (int n = tid; n < NP; n += 256) { sx += px[n]; sy += py[n]; sz += pz[n]; }
  __shared__ double rx[256], ry[256], rz[256];
  rx[tid]=sx; ry[tid]=sy; rz[tid]=sz;
  __syncthreads();
  for (int s = 128; s > 0; s >>= 1) {
    if (tid < s) { rx[tid]+=rx[tid+s]; ry[tid]+=ry[tid+s]; rz[tid]+=rz[tid+s]; }
    __syncthreads();
  }
  __shared__ float cxs, cys, czs;
  if (tid == 0) {
    cxs = (float)(rx[0]/NP); cys = (float)(ry[0]/NP); czs = (float)(rz[0]/NP);
  }
  __syncthreads();
  float cx = cxs, cy = cys, cz = czs;
  for (int n = tid; n < NP; n += 256) {
    float dx = __fsub_rn(px[n], cx);
    float dy = __fsub_rn(py[n], cy);
    float dz = __fsub_rn(pz[n], cz);
    float d = __fadd_rn(__fadd_rn(__fmul_rn(dx,dx), __fmul_rn(dy,dy)), __fmul_rn(dz,dz));
    dcent[b*NP + n] = d;
    rankb[b*NP + n] = 0;
  }
}

// float4 LDS reads (kept from R15: measured ~10 us win)
__global__ void __launch_bounds__(256) k_rank_part(const float* __restrict__ dcent,
                                                   int* __restrict__ rank) {
  int jc = blockIdx.x, ic = blockIdx.y, b = blockIdx.z;
  __shared__ __attribute__((aligned(16))) float d[JCH];
  int j0 = jc*JCH;
  for (int n = threadIdx.x; n < JCH; n += 256) d[n] = dcent[b*NP + j0 + n];
  __syncthreads();
  int i = ic*256 + threadIdx.x;
  float di = dcent[b*NP + i];
  int cnt = 0;
  #pragma unroll 4
  for (int n = 0; n < JCH; n += 4) {
    float4 dv = *(const float4*)&d[n];     // ds_read_b128: 4 candidates per LDS op
    cnt += (dv.x < di) || (dv.x == di && (j0 + n + 0) < i);
    cnt += (dv.y < di) || (dv.y == di && (j0 + n + 1) < i);
    cnt += (dv.z < di) || (dv.z == di && (j0 + n + 2) < i);
    cnt += (dv.w < di) || (dv.w == di && (j0 + n + 3) < i);
  }
  atomicAdd(&rank[b*NP + i], cnt);
}

// scatter + build rank-sorted tables + zero deg (merged)
__global__ void k_scatprep(const float* __restrict__ pc, const int* __restrict__ rank,
                           const float* __restrict__ dcent,
                           int* __restrict__ ord, float4* __restrict__ srt,
                           float* __restrict__ rcv, int* __restrict__ deg) {
  int idx = blockIdx.x*256 + threadIdx.x;
  int b = idx >> 12, i = idx & (NP-1);
  int r = rank[idx];
  ord[b*NP + r] = i;
  const float* base = pc + (size_t)b*3*NP;
  float x = base[i], y = base[NP+i], z = base[2*NP+i];
  float sq = __fadd_rn(__fadd_rn(__fmul_rn(x,x), __fmul_rn(y,y)), __fmul_rn(z,z));
  float4 v; v.x=x; v.y=y; v.z=z; v.w=sq;
  srt[b*NP + r] = v;
  rcv[b*NP + r] = sqrtf(dcent[idx]);
  deg[idx] = 0;
}

// ---- annulus KNN v4.1 (measured best: 74.9 us): sentinel tile in LDS, rc in global ----
#define INS(dist, q) \
  if (dist < b4) { \
    if (dist < b3) { b4=b3; r4=r3; \
      if (dist < b2) { b3=b2; r3=r2; \
        if (dist < b1) { b2=b1; r2=r1; \
          if (dist < b0) { b1=b0; r1=r0; b0=dist; r0=(q); } \
          else { b1=dist; r1=(q); } \
        } else { b2=dist; r2=(q); } \
      } else { b3=dist; r3=(q); } \
    } else { b4=dist; r4=(q); } \
  }

__global__ void __launch_bounds__(512) k_knn_ann4(const float4* __restrict__ srt,
                                                  const float* __restrict__ rc,
                                                  const int* __restrict__ ord,
                                                  int* __restrict__ nbr,
                                                  int* __restrict__ deg) {
  __shared__ float4 tile[NP + 2*SENT];   // 67584 B -> 2 blocks/CU
  int b = blockIdx.x >> 6;        // 64 blocks per batch
  int blk = blockIdx.x & 63;
  int gbase = b*NP;
  for (int t = threadIdx.x; t < NP + 2*SENT; t += 512) {
    int q = t - SENT;
    if ((unsigned)q < NP) tile[t] = srt[gbase + q];
    else { float4 s4; s4.x=0.f; s4.y=0.f; s4.z=0.f; s4.w=1e30f; tile[t] = s4; }
  }
  __syncthreads();

  const int lane = threadIdx.x & 63;
  const int wv   = threadIdx.x >> 6;   // 8 waves
  const int grp  = lane >> 3;          // 8 groups of 8 lanes per wave
  const int sub  = lane & 7;
  const int s_i  = blk*64 + wv*8 + grp;

  float4 p = tile[SENT + s_i];
  float xi=p.x, yi=p.y, zi=p.z, sqi=p.w;
  float ri = rc[gbase + s_i];

  const bool is_hi = (sub < 4);
  const int step = is_hi ? 4 : -4;
  const int jdead = is_hi ? (NP + 7) : (-36);  // frozen cursor -> sentinel region
  int j = is_hi ? (s_i + sub) : (s_i - 1 - (sub - 4));
  bool alive = ((unsigned)j < NP);
  if (!alive) j = jdead;

  float b0=FLT_MAX, b1=FLT_MAX, b2=FLT_MAX, b3=FLT_MAX, b4=FLT_MAX;
  int r0=0, r1=0, r2=0, r3=0, r4=0;

  while (__ballot(alive)) {
    float4 jp[8];
    #pragma unroll
    for (int t = 0; t < 8; ++t) jp[t] = tile[SENT + j + step*t];
    #pragma unroll
    for (int t = 0; t < 8; ++t) {
      float dot = __fadd_rn(__fadd_rn(__fmul_rn(xi,jp[t].x), __fmul_rn(yi,jp[t].y)), __fmul_rn(zi,jp[t].z));
      float dist = __fsub_rn(__fadd_rn(sqi, jp[t].w), __fmul_rn(2.0f, dot));
      if (__ballot(dist < b4)) { INS(dist, j + step*t) }
    }
    // group-shared prune bound (min of per-lane b4 over the 8-lane group)
    float bm = b4;
    bm = fminf(bm, __shfl_xor(bm, 1));
    bm = fminf(bm, __shfl_xor(bm, 2));
    bm = fminf(bm, __shfl_xor(bm, 4));
    float T = bm*1.0002f + 1e-9f;
    int qe = j + step*7;
    qe = qe < 0 ? 0 : (qe > NP-1 ? NP-1 : qe);
    float dr = fabsf(ri - rc[gbase + qe]);
    bool nextin = ((unsigned)(j + step*8) < NP);
    alive = alive && nextin && (__fmul_rn(dr,dr) < T);
    j = alive ? (j + step*8) : jdead;
  }

  // merge the 8 sorted-5 lists within the group (xor butterfly)
  #pragma unroll
  for (int m = 1; m <= 4; m <<= 1) {
    float c0=__shfl_xor(b0,m), c1=__shfl_xor(b1,m), c2=__shfl_xor(b2,m),
          c3=__shfl_xor(b3,m), c4=__shfl_xor(b4,m);
    int   s0=__shfl_xor(r0,m), s1=__shfl_xor(r1,m), s2=__shfl_xor(r2,m),
          s3=__shfl_xor(r3,m), s4=__shfl_xor(r4,m);
    if (c0 < b4) { INS(c0, s0)
      if (c1 < b4) { INS(c1, s1)
        if (c2 < b4) { INS(c2, s2)
          if (c3 < b4) { INS(c3, s3)
            if (c4 < b4) { INS(c4, s4) }
          }
        }
      }
    }
  }

  if (sub == 0) {
    int oi = ord[gbase + s_i];
    int node = gbase + oi;
    int nb = node*KNN;
    int o0 = gbase + ord[gbase+r0], o1 = gbase + ord[gbase+r1], o2 = gbase + ord[gbase+r2];
    int o3 = gbase + ord[gbase+r3], o4 = gbase + ord[gbase+r4];
    nbr[nb+0]=o0; nbr[nb+1]=o1; nbr[nb+2]=o2; nbr[nb+3]=o3; nbr[nb+4]=o4;
    atomicAdd(&deg[o0],1); atomicAdd(&deg[o1],1); atomicAdd(&deg[o2],1);
    atomicAdd(&deg[o3],1); atomicAdd(&deg[o4],1);
  }
}

// ---------------- all weights fp32->bf16 in one launch ----------------
__global__ void k_cvt_all(const float* __restrict__ w2, const float* __restrict__ w3,
                          const float* __restrict__ w4, const float* __restrict__ gc1,
                          const float* __restrict__ gc2, const float* __restrict__ gc3,
                          const float* __restrict__ fc1, const float* __restrict__ fc2,
                          u16* o2, u16* o3, u16* o4, u16* og1, u16* og2, u16* og3,
                          u16* of1, u16* of2) {
  int i = blockIdx.x*256 + threadIdx.x;
  if (i < 4096) { o2[i] = f2bf(w2[i]); return; } i -= 4096;
  if (i < 4096) { o3[i] = f2bf(w3[i]); return; } i -= 4096;
  if (i < 8192) { o4[i] = f2bf(w4[i]); return; } i -= 8192;
  if (i < 16384) { int n=i>>7, k=i&127; og1[i] = f2bf(gc1[k*128+n]); return; } i -= 16384;
  if (i < 16384) { int n=i>>7, k=i&127; og2[i] = f2bf(gc2[k*128+n]); return; } i -= 16384;
  if (i < 32768) { int n=i>>7, k=i&127; og3[i] = f2bf(gc3[k*256+n]); return; } i -= 32768;
  if (i < 131072) { of1[i] = f2bf(fc1[i]); return; } i -= 131072;
  if (i < 131072) { of2[i] = f2bf(fc2[i]); }
}

// ---------------- fused conv stack: conv1 (3->64) + conv2/3 (64->64) + conv4 (64->128) ----
__global__ void __launch_bounds__(256) k_convstack(
    const float* __restrict__ pc, const int* __restrict__ ord,
    const float* __restrict__ w1, const float* __restrict__ g1, const float* __restrict__ b1,
    const u16* __restrict__ wb2, const float* __restrict__ g2, const float* __restrict__ b2,
    const u16* __restrict__ wb3, const float* __restrict__ g3, const float* __restrict__ b3,
    const u16* __restrict__ wb4, const float* __restrict__ g4, const float* __restrict__ b4,
    u16* __restrict__ feat, float* __restrict__ pooled) {
  __shared__ float xs[128], ys[128], zs[128];
  __shared__ u16 hA[128*64];
  __shared__ u16 hB[128*64];
  __shared__ u16 wbuf[128*64];
  const int tid = threadIdx.x;
  const int m0 = blockIdx.x * 128;
  const int b = m0 >> 12;
  if (blockIdx.x == 0) pooled[tid] = 0.0f;
  if (tid < 128) {
    int j = ord[m0 + tid];
    const float* base = pc + (size_t)b*3*NP;
    xs[tid] = base[j]; ys[tid] = base[NP + j]; zs[tid] = base[2*NP + j];
  }
  #pragma unroll
  for (int it = 0; it < 2; ++it) {
    int t = tid + it*256;
    int row = t >> 3, lc = t & 7;
    uint4 v = *(const uint4*)(wb2 + ((size_t)row*64 + lc*8));
    *(uint4*)&wbuf[row*64 + ((lc ^ (row&7))*8)] = v;
  }
  __syncthreads();

  for (int idx = tid; idx < 128*64; idx += 256) {
    int n = idx >> 6, o = idx & 63;
    float x = xs[n], y = ys[n], z = zs[n];
    float acc = x*w1[o*3+0] + y*w1[o*3+1] + z*w1[o*3+2];
    float v = fmaxf(acc*g1[o] + b1[o], 0.0f);
    hA[n*64 + (((o>>3) ^ (n&7))*8) + (o&7)] = f2bf(v);
  }
  __syncthreads();

  const int w = tid >> 6, l = tid & 63;
  const int wm = w & 1, wn = w >> 1;
  const int fm = l & 15, fk = l >> 4;

  // ---- conv2 ----
  {
    f32x4 acc[4][2];
    #pragma unroll
    for (int i=0;i<4;++i) { acc[i][0]=(f32x4){0,0,0,0}; acc[i][1]=(f32x4){0,0,0,0}; }
    #pragma unroll
    for (int ks=0; ks<2; ++ks){
      bf16x8 af[4], bfr[2];
      #pragma unroll
      for (int mf=0; mf<4; ++mf){
        int row = wm*64 + mf*16 + fm; int ck = ks*4 + fk;
        af[mf] = *(const bf16x8*)&hA[row*64 + ((ck ^ (row&7))*8)];
      }
      #pragma unroll
      for (int nf=0; nf<2; ++nf){
        int row = wn*32 + nf*16 + fm; int ck = ks*4 + fk;
        bfr[nf] = *(const bf16x8*)&wbuf[row*64 + ((ck ^ (row&7))*8)];
      }
      #pragma unroll
      for (int mf=0; mf<4; ++mf)
        #pragma unroll
        for (int nf=0; nf<2; ++nf)
          acc[mf][nf] = __builtin_amdgcn_mfma_f32_16x16x32_bf16(af[mf], bfr[nf], acc[mf][nf], 0, 0, 0);
    }
    #pragma unroll
    for (int mf=0; mf<4; ++mf)
      #pragma unroll
      for (int r=0;r<4;++r){
        int row = wm*64 + mf*16 + fk*4 + r;
        #pragma unroll
        for (int nf=0;nf<2;++nf){
          int col = wn*32 + nf*16 + fm;
          float v = fmaxf(acc[mf][nf][r]*g2[col] + b2[col], 0.f);
          hB[row*64 + (((col>>3) ^ (row&7))*8) + (col&7)] = f2bf(v);
        }
      }
  }
  __syncthreads();
  #pragma unroll
  for (int it = 0; it < 2; ++it) {
    int t = tid + it*256;
    int row = t >> 3, lc = t & 7;
    uint4 v = *(const uint4*)(wb3 + ((size_t)row*64 + lc*8));
    *(uint4*)&wbuf[row*64 + ((lc ^ (row&7))*8)] = v;
  }
  __syncthreads();

  // ---- conv3 ----
  {
    f32x4 acc[4][2];
    #pragma unroll
    for (int i=0;i<4;++i) { acc[i][0]=(f32x4){0,0,0,0}; acc[i][1]=(f32x4){0,0,0,0}; }
    #pragma unroll
    for (int ks=0; ks<2; ++ks){
      bf16x8 af[4], bfr[2];
      #pragma unroll
      for (int mf=0; mf<4; ++mf){
        int row = wm*64 + mf*16 + fm; int ck = ks*4 + fk;
        af[mf] = *(const bf16x8*)&hB[row*64 + ((ck ^ (row&7))*8)];
      }
      #pragma unroll
      for (int nf=0; nf<2; ++nf){
        int row = wn*32 + nf*16 + fm; int ck = ks*4 + fk;
        bfr[nf] = *(const bf16x8*)&wbuf[row*64 + ((ck ^ (row&7))*8)];
      }
      #pragma unroll
      for (int mf=0; mf<4; ++mf)
        #pragma unroll
        for (int nf=0; nf<2; ++nf)
          acc[mf][nf] = __builtin_amdgcn_mfma_f32_16x16x32_bf16(af[mf], bfr[nf], acc[mf][nf], 0, 0, 0);
    }
    #pragma unroll
    for (int mf=0; mf<4; ++mf)
      #pragma unroll
      for (int r=0;r<4;++r){
        int row = wm*64 + mf*16 + fk*4 + r;
        #pragma unroll
        for (int nf=0;nf<2;++nf){
          int col = wn*32 + nf*16 + fm;
          float v = fmaxf(acc[mf][nf][r]*g3[col] + b3[col], 0.f);
          hA[row*64 + (((col>>3) ^ (row&7))*8) + (col&7)] = f2bf(v);
        }
      }
  }
  __syncthreads();
  #pragma unroll
  for (int it = 0; it < 4; ++it) {
    int t = tid + it*256;
    int row = t >> 3, lc = t & 7;
    uint4 v = *(const uint4*)(wb4 + ((size_t)row*64 + lc*8));
    *(uint4*)&wbuf[row*64 + ((lc ^ (row&7))*8)] = v;
  }
  __syncthreads();

  // ---- conv4 ----
  {
    f32x4 acc[4][4];
    #pragma unroll
    for (int i=0;i<4;++i)
      #pragma unroll
      for (int jn=0;jn<4;++jn) acc[i][jn]=(f32x4){0,0,0,0};
    #pragma unroll
    for (int ks=0; ks<2; ++ks){
      bf16x8 af[4], bfr[4];
      #pragma unroll
      for (int mf=0; mf<4; ++mf){
        int row = wm*64 + mf*16 + fm; int ck = ks*4 + fk;
        af[mf] = *(const bf16x8*)&hA[row*64 + ((ck ^ (row&7))*8)];
      }
      #pragma unroll
      for (int nf=0; nf<4; ++nf){
        int row = wn*64 + nf*16 + fm; int ck = ks*4 + fk;
        bfr[nf] = *(const bf16x8*)&wbuf[row*64 + ((ck ^ (row&7))*8)];
      }
      #pragma unroll
      for (int mf=0; mf<4; ++mf)
        #pragma unroll
        for (int nf=0; nf<4; ++nf)
          acc[mf][nf] = __builtin_amdgcn_mfma_f32_16x16x32_bf16(af[mf], bfr[nf], acc[mf][nf], 0, 0, 0);
    }
    #pragma unroll
    for (int mf=0; mf<4; ++mf)
      #pragma unroll
      for (int r=0;r<4;++r){
        int row = m0 + wm*64 + mf*16 + fk*4 + r;
        #pragma unroll
        for (int nf=0;nf<4;++nf){
          int col = wn*64 + nf*16 + fm;
          float v = fmaxf(acc[mf][nf][r]*g4[col] + b4[col], 0.f);
          feat[(size_t)row*128 + col] = f2bf(v);
        }
      }
  }
}

// ---------------- bf16 MFMA GEMM: C = act(A[M,K] * W[N,K]^T) ----------------
// mode 0: bf16 out = relu(acc*gamma[col]+beta[col])
// mode 1: bf16 out = acc * (1/sqrt(max(deg[row],1)))
// mode 3: no C write; atomicMax global max-pool of relu(acc*gamma[col]+beta[col]) into Cout
template<int BNT>
__global__ __launch_bounds__(256) void gemm_bf16(
    const u16* __restrict__ A, const u16* __restrict__ W,
    const float* __restrict__ gamma, const float* __restrict__ beta,
    const int* __restrict__ degp, void* __restrict__ Cout,
    int K, int Nc, int mode) {
  constexpr int NF = BNT/32;
  __shared__ u16 As[128*64];
  __shared__ u16 Bs[BNT*64];
  const int tid = threadIdx.x;
  const int w = tid >> 6, l = tid & 63;
  const int m0 = blockIdx.x*128, n0 = blockIdx.y*BNT;
  const int wm = w & 1, wn = w >> 1;
  const int lr = l >> 3;
  const int lc = l & 7;
  const int fm = l & 15, fk = l >> 4;

  f32x4 acc[4][NF];
  #pragma unroll
  for (int i=0;i<4;++i)
    #pragma unroll
    for (int j=0;j<NF;++j) acc[i][j] = (f32x4){0.f,0.f,0.f,0.f};

  for (int k0 = 0; k0 < K; k0 += 64) {
    #pragma unroll
    for (int t=0;t<4;++t){
      int row = (w*4 + t)*8 + lr;
      uint4 v = *(const uint4*)(A + ((size_t)(m0+row)*K + k0 + lc*8));
      *(uint4*)&As[row*64 + ((lc ^ (row&7))*8)] = v;
    }
    #pragma unroll
    for (int t=0;t<NF;++t){
      int row = (w*NF + t)*8 + lr;
      uint4 v = *(const uint4*)(W + ((size_t)(n0+row)*K + k0 + lc*8));
      *(uint4*)&Bs[row*64 + ((lc ^ (row&7))*8)] = v;
    }
    __syncthreads();
    #pragma unroll
    for (int ks=0; ks<2; ++ks){
      bf16x8 af[4], bfr[NF];
      #pragma unroll
      for (int mf=0; mf<4; ++mf){
        int row = wm*64 + mf*16 + fm;
        int ck = ks*4 + fk;
        af[mf] = *(const bf16x8*)&As[row*64 + ((ck ^ (row&7))*8)];
      }
      #pragma unroll
      for (int nf=0; nf<NF; ++nf){
        int row = wn*(BNT/2) + nf*16 + fm;
        int ck = ks*4 + fk;
        bfr[nf] = *(const bf16x8*)&Bs[row*64 + ((ck ^ (row&7))*8)];
      }
      #pragma unroll
      for (int mf=0; mf<4; ++mf)
        #pragma unroll
        for (int nf=0; nf<NF; ++nf)
          acc[mf][nf] = __builtin_amdgcn_mfma_f32_16x16x32_bf16(af[mf], bfr[nf], acc[mf][nf], 0, 0, 0);
    }
    __syncthreads();
  }

  const int col_base = n0 + wn*(BNT/2);
  if (mode == 1) {
    u16* C = (u16*)Cout;
    #pragma unroll
    for (int mf=0; mf<4; ++mf){
      #pragma unroll
      for (int r=0;r<4;++r){
        int row = m0 + wm*64 + mf*16 + fk*4 + r;
        int d = degp[row]; if (d < 1) d = 1;
        float rs = 1.0f / sqrtf((float)d);
        #pragma unroll
        for (int nf=0;nf<NF;++nf){
          int col = col_base + nf*16 + fm;
          C[(size_t)row*Nc + col] = f2bf(acc[mf][nf][r]*rs);
        }
      }
    }
  } else if (mode == 3) {
    unsigned int* pool = (unsigned int*)Cout;
    float gv[NF], bv[NF], cm[NF];
    #pragma unroll
    for (int nf=0;nf<NF;++nf){
      int col = col_base + nf*16 + fm;
      gv[nf] = gamma[col]; bv[nf] = beta[col];
      cm[nf] = 0.0f;
    }
    #pragma unroll
    for (int mf=0; mf<4; ++mf)
      #pragma unroll
      for (int r=0;r<4;++r)
        #pragma unroll
        for (int nf=0;nf<NF;++nf){
          float v = fmaxf(acc[mf][nf][r]*gv[nf] + bv[nf], 0.f);
          cm[nf] = fmaxf(cm[nf], v);
        }
    #pragma unroll
    for (int nf=0;nf<NF;++nf){
      float m = cm[nf];
      m = fmaxf(m, __shfl_xor(m, 16));
      m = fmaxf(m, __shfl_xor(m, 32));
      if (fk == 0)
        atomicMax(&pool[col_base + nf*16 + fm], __float_as_uint(m));
    }
  } else {
    float gv[NF], bv[NF];
    #pragma unroll
    for (int nf=0;nf<NF;++nf){
      int col = col_base + nf*16 + fm;
      gv[nf] = gamma[col]; bv[nf] = beta[col];
    }
    #pragma unroll
    for (int mf=0; mf<4; ++mf){
      #pragma unroll
      for (int r=0;r<4;++r){
        int row = m0 + wm*64 + mf*16 + fk*4 + r;
        #pragma unroll
        for (int nf=0;nf<NF;++nf){
          int col = col_base + nf*16 + fm;
          float v = fmaxf(acc[mf][nf][r]*gv[nf] + bv[nf], 0.f);
          ((u16*)Cout)[(size_t)row*Nc + col] = f2bf(v);
        }
      }
    }
  }
}

// ---------------- GCN aggregate (bf16 in/out, fp32 math) ----------------
__global__ void k_agg_bf(const u16* __restrict__ hw, const int* __restrict__ nbr,
                         const float* __restrict__ bias, u16* __restrict__ outp,
                         int F, int do_relu) {
  int per = F >> 3;
  int gid = blockIdx.x*256 + threadIdx.x;
  int i = gid / per;
  int f = (gid - i*per) * 8;
  const int* nb = nbr + i*KNN;
  float s[8] = {0,0,0,0,0,0,0,0};
  #pragma unroll
  for (int k = 0; k < KNN; ++k) {
    uint4 v = *(const uint4*)(hw + (size_t)nb[k]*F + f);
    const u16* h = (const u16*)&v;
    #pragma unroll
    for (int j=0;j<8;++j) s[j] += bf2f(h[j]);
  }
  const float ninv = 0.44721359549995793f;  // rsqrt(5): deg_in == 5 always
  u16 o[8];
  #pragma unroll
  for (int j=0;j<8;++j){
    float v = s[j]*ninv + bias[f+j];
    if (do_relu) v = fmaxf(v, 0.f);
    o[j] = f2bf(v);
  }
  *(uint4*)&outp[(size_t)i*F + f] = *(const uint4*)o;
}

// ---------------- final 256 -> 128 GEMV (fp32) ----------------
__global__ void k_fc3(const float* __restrict__ pooled, const float* __restrict__ w,
                      const float* __restrict__ bias, float* __restrict__ outp) {
  __shared__ float p[256];
  int tid = threadIdx.x;
  p[tid] = pooled[tid];
  p[tid + 128] = pooled[tid + 128];
  __syncthreads();
  float s = 0.0f;
  for (int i = 0; i < 256; ++i) s = fmaf(w[tid*256 + i], p[i], s);
  outp[tid] = s + bias[tid];
}

extern "C" void kernel_launch(void* const* d_in, const int* in_sizes, int n_in,
                              void* d_out, int out_size, void* d_ws, size_t ws_size,
                              hipStream_t stream) {
  const float* pc   = (const float*)d_in[0];
  const float* w1   = (const float*)d_in[1];
  const float* g1   = (const float*)d_in[2];
  const float* b1   = (const float*)d_in[3];
  const float* w2   = (const float*)d_in[4];
  const float* g2   = (const float*)d_in[5];
  const float* b2   = (const float*)d_in[6];
  const float* w3   = (const float*)d_in[7];
  const float* g3   = (const float*)d_in[8];
  const float* b3   = (const float*)d_in[9];
  const float* w4   = (const float*)d_in[10];
  const float* g4   = (const float*)d_in[11];
  const float* b4   = (const float*)d_in[12];
  const float* gc1w = (const float*)d_in[13];
  const float* gc1b = (const float*)d_in[14];
  const float* gc2w = (const float*)d_in[15];
  const float* gc2b = (const float*)d_in[16];
  const float* gc3w = (const float*)d_in[17];
  const float* gc3b = (const float*)d_in[18];
  const float* fc1w = (const float*)d_in[19];
  const float* f1g  = (const float*)d_in[20];
  const float* f1b  = (const float*)d_in[21];
  const float* fc2w = (const float*)d_in[22];
  const float* f2g  = (const float*)d_in[23];
  const float* f2b  = (const float*)d_in[24];
  const float* fc3w = (const float*)d_in[25];
  const float* fc3b = (const float*)d_in[26];
  float* outp = (float*)d_out;

  char* wsb = (char*)d_ws;
  size_t off = 0;
  auto alloc = [&](size_t bytes) -> void* {
    void* p = wsb + off;
    off += (bytes + 255) & ~(size_t)255;
    return p;
  };
  int*   ord    = (int*)  alloc((size_t)BN_*4);
  int*   deg    = (int*)  alloc((size_t)BN_*4);
  int*   rankb  = (int*)  alloc((size_t)BN_*4);
  int*   nbr    = (int*)  alloc((size_t)BN_*KNN*4);
  float* dcent  = (float*)alloc((size_t)BN_*4);
  float* pooled = (float*)alloc(256*4);
  float4* srt   = (float4*)alloc((size_t)BN_*16);
  float* rc     = (float*)alloc((size_t)BN_*4);
  // bf16 weights
  u16* wb2   = (u16*)alloc(64*64*2);
  u16* wb3   = (u16*)alloc(64*64*2);
  u16* wb4   = (u16*)alloc(128*64*2);
  u16* wgc1  = (u16*)alloc(128*128*2);
  u16* wgc2  = (u16*)alloc(128*128*2);
  u16* wgc3  = (u16*)alloc(256*128*2);
  u16* wfc1  = (u16*)alloc(512*256*2);
  u16* wfc2  = (u16*)alloc(256*512*2);
  // bf16 activations
  u16* feat = (u16*)alloc((size_t)BN_*128*2);
  u16* hw   = (u16*)alloc((size_t)BN_*256*2);
  u16* gb1  = (u16*)alloc((size_t)BN_*128*2);
  u16* g3b  = (u16*)alloc((size_t)BN_*256*2);
  u16* z1   = (u16*)alloc((size_t)BN_*512*2);

  k_cvt_all<<<1344, 256, 0, stream>>>(w2, w3, w4, gc1w, gc2w, gc3w, fc1w, fc2w,
                                      wb2, wb3, wb4, wgc1, wgc2, wgc3, wfc1, wfc2);

  // preprocessing (exact fp32)
  k_centroid<<<NB, 256, 0, stream>>>(pc, dcent, rankb);
  k_rank_part<<<dim3(NJC, NP/256, NB), 256, 0, stream>>>(dcent, rankb);
  k_scatprep<<<BN_/256, 256, 0, stream>>>(pc, rankb, dcent, ord, srt, rc, deg);
  k_knn_ann4<<<NB*64, 512, 0, stream>>>(srt, rc, ord, nbr, deg);

  // fused conv stack: conv1 + conv2 + conv3 + conv4 -> feat [BN,128]
  k_convstack<<<BN_/128, 256, 0, stream>>>(pc, ord, w1, g1, b1,
                                           wb2, g2, b2, wb3, g3, b3, wb4, g4, b4,
                                           feat, pooled);

  // GCN 1
  gemm_bf16<128><<<dim3(BN_/128, 1), 256, 0, stream>>>(feat, wgc1, nullptr, nullptr, deg, hw, 128, 128, 1);
  k_agg_bf<<<(BN_*16)/256, 256, 0, stream>>>(hw, nbr, gc1b, gb1, 128, 1);
  // GCN 2
  gemm_bf16<128><<<dim3(BN_/128, 1), 256, 0, stream>>>(gb1, wgc2, nullptr, nullptr, deg, hw, 128, 128, 1);
  k_agg_bf<<<(BN_*16)/256, 256, 0, stream>>>(hw, nbr, gc2b, feat, 128, 1);
  // GCN 3
  gemm_bf16<128><<<dim3(BN_/128, 2), 256, 0, stream>>>(feat, wgc3, nullptr, nullptr, deg, hw, 128, 256, 1);
  k_agg_bf<<<(BN_*32)/256, 256, 0, stream>>>(hw, nbr, gc3b, g3b, 256, 0);

  // head: fc1 -> z1; fc2 fused with global max-pool (mode 3, no C write)
  gemm_bf16<128><<<dim3(BN_/128, 4), 256, 0, stream>>>(g3b, wfc1, f1g, f1b, nullptr, z1, 256, 512, 0);
  gemm_bf16<128><<<dim3(BN_/128, 2), 256, 0, stream>>>(z1, wfc2, f2g, f2b, nullptr, pooled, 512, 256, 3);
  k_fc3<<<1, 128, 0, stream>>>(pooled, fc3w, fc3b, outp);
}